// Round 16
// baseline (82.512 us; speedup 1.0000x reference)
//
#include <hip/hip_runtime.h>
#include <hip/hip_bf16.h>
#include <stdint.h>

#define VOCAB 200000
#define EDIM 128
#define NTREES 2048
#define KNODES 511

typedef __attribute__((ext_vector_type(4))) float f32x4;
typedef __attribute__((ext_vector_type(2))) float f32x2;
typedef __attribute__((ext_vector_type(8))) short s16x8;
typedef __attribute__((ext_vector_type(8))) unsigned short u16x8;
typedef __attribute__((ext_vector_type(4))) unsigned int u32x4;

#define AS1 __attribute__((address_space(1)))
#define AS3 __attribute__((address_space(3)))

__device__ __forceinline__ unsigned short f2bf(float x) {
  unsigned u = __builtin_bit_cast(unsigned, x);
  return (unsigned short)((u + 0x7fffu + ((u >> 16) & 1u)) >> 16);  // RNE
}
__device__ __forceinline__ float bf2f(unsigned short h) {
  unsigned u = ((unsigned)h) << 16;
  return __builtin_bit_cast(float, u);
}

// ---- manual OCP e4m3fn codec (fallback paths only) ----
__device__ __forceinline__ unsigned fp8enc(float v) {
  unsigned u = __builtin_bit_cast(unsigned, v);
  unsigned s = (u >> 24) & 0x80u;
  unsigned au = u & 0x7fffffffu;
  au = au > 0x43E00000u ? 0x43E00000u : au;
  unsigned r = au + 0x0007ffffu + ((au >> 20) & 1u);
  unsigned code = (((r >> 23) - 120u) << 3) | ((r >> 20) & 7u);
  float a = __builtin_bit_cast(float, au);
  unsigned sub = (unsigned)(int)rintf(a * 512.0f);
  unsigned c = (au < 0x3C800000u) ? sub : code;
  return c | s;
}
__device__ __forceinline__ float fp8dec(unsigned b) {
  unsigned e = (b >> 3) & 15u, m = b & 7u;
  float n = __builtin_bit_cast(float, ((e + 120u) << 23) | (m << 20));
  float sv = (float)(int)m * 0.001953125f;
  float v = e ? n : sv;
  return (b & 0x80u) ? -v : v;
}

__device__ __forceinline__ unsigned enc4(float a, float b, float c, float d) {
#if __has_builtin(__builtin_amdgcn_cvt_pk_fp8_f32)
  int pk = 0;
  pk = __builtin_amdgcn_cvt_pk_fp8_f32(a, b, pk, false);
  pk = __builtin_amdgcn_cvt_pk_fp8_f32(c, d, pk, true);
  return (unsigned)pk;
#else
  return fp8enc(a) | (fp8enc(b) << 8) | (fp8enc(c) << 16) | (fp8enc(d) << 24);
#endif
}

__device__ __forceinline__ void dec8(uint2 v, float* o) {
#if __has_builtin(__builtin_amdgcn_cvt_pk_f32_fp8)
  f32x2 a = __builtin_amdgcn_cvt_pk_f32_fp8(v.x, false);
  f32x2 b = __builtin_amdgcn_cvt_pk_f32_fp8(v.x, true);
  f32x2 c = __builtin_amdgcn_cvt_pk_f32_fp8(v.y, false);
  f32x2 d = __builtin_amdgcn_cvt_pk_f32_fp8(v.y, true);
  o[0] = a[0]; o[1] = a[1]; o[2] = b[0]; o[3] = b[1];
  o[4] = c[0]; o[5] = c[1]; o[6] = d[0]; o[7] = d[1];
#else
#pragma unroll
  for (int i = 0; i < 4; ++i) o[i] = fp8dec((v.x >> (8 * i)) & 0xFFu);
#pragma unroll
  for (int i = 0; i < 4; ++i) o[4 + i] = fp8dec((v.y >> (8 * i)) & 0xFFu);
#endif
}

__device__ __forceinline__ s16x8 cvt8(f32x4 a, f32x4 b) {
  u16x8 t;
#pragma unroll
  for (int i = 0; i < 4; ++i)
    t[i] = __builtin_bit_cast(unsigned short, __float2bfloat16(a[i]));
#pragma unroll
  for (int i = 0; i < 4; ++i)
    t[4 + i] = __builtin_bit_cast(unsigned short, __float2bfloat16(b[i]));
  return __builtin_bit_cast(s16x8, t);
}

// ---------------- Kernel 0: one-shot W/bias prep, fragment-major ----------------
__global__ __launch_bounds__(256) void wprep_kernel(
    const float* __restrict__ W, const float* __restrict__ b,
    unsigned short* __restrict__ WTb2, float* __restrict__ bsc) {
  int c = blockIdx.x * 256 + threadIdx.x;   // 0..2047
  if (c < 2048) {
    int lane = c & 63, fr = c >> 6;
    int ks = fr >> 3, nt = fr & 7, q = lane >> 4, cl = lane & 15;
    u16x8 t;
#pragma unroll
    for (int j = 0; j < 8; ++j)
      t[j] = f2bf(W[(ks * 32 + q * 8 + j) * EDIM + nt * 16 + cl] * 64.0f);
    *(u16x8*)(WTb2 + c * 8) = t;
  }
  if (c < EDIM) bsc[c] = b[c] * 64.0f;
}

// ---------------- Kernel 1: T8 = fp8( emb @ W*64 + b*64 ) — one-shot, PINNED loads ----------------
// R15 + two changes: (1) launch_bounds(256,2) -> 256-reg budget so the 16 emb vectors
// actually FIT in registers; (2) asm pins after issue — the compiler can no longer sink
// the __restrict__ loads past the barrier into the MFMA loop (the R7 disease).
__global__ __launch_bounds__(256, 2) void proj_kernel(
    const float* __restrict__ emb, const unsigned short* __restrict__ WTb2,
    const float* __restrict__ bsc, unsigned char* __restrict__ T8) {
  __shared__ unsigned short WL[2048 * 8];   // 32 KiB fragment-major
  __shared__ float LB[EDIM];                // 512 B
  __shared__ char ST[4][32 * 144];          // 18 KiB store stage

  const int tid = threadIdx.x;
  const int wv = tid >> 6, lane = tid & 63;
  const int q = lane >> 4, cl = lane & 15;

  // issue the block's emb working set: 16 independent f32x4 loads per thread
  const long rowbase = (long)blockIdx.x * 128 + wv * 32;
  long r0 = rowbase + cl, r1 = rowbase + 16 + cl;
  if (r0 >= VOCAB) r0 = VOCAB - 1;          // tail: dup LOADS only (broadcast-safe)
  if (r1 >= VOCAB) r1 = VOCAB - 1;
  const float* p0 = emb + r0 * EDIM + q * 8;
  const float* p1 = emb + r1 * EDIM + q * 8;
  f32x4 ea0[4], eb0[4], ea1[4], eb1[4];
#pragma unroll
  for (int ks = 0; ks < 4; ++ks) {
    ea0[ks] = *(const f32x4*)(p0 + ks * 32);
    eb0[ks] = *(const f32x4*)(p0 + ks * 32 + 4);
    ea1[ks] = *(const f32x4*)(p1 + ks * 32);
    eb1[ks] = *(const f32x4*)(p1 + ks * 32 + 4);
  }
  // PIN: force all 16 vectors to be materialized here (no sinking/remat)
#pragma unroll
  for (int ks = 0; ks < 4; ++ks) {
    asm volatile("" : "+v"(ea0[ks]));
    asm volatile("" : "+v"(eb0[ks]));
    asm volatile("" : "+v"(ea1[ks]));
    asm volatile("" : "+v"(eb1[ks]));
  }

  // stage W into LDS (8 x 1KB DMA per wave, linear dest) + bias
#pragma unroll
  for (int i = 0; i < 8; ++i) {
    const char* src = (const char*)WTb2 + wv * 8192 + i * 1024 + lane * 16;
    char* dstp = (char*)WL + wv * 8192 + i * 1024;
    __builtin_amdgcn_global_load_lds((const AS1 unsigned int*)src,
                                     (AS3 unsigned int*)dstp, 16, 0, 0);
  }
  if (tid < EDIM) LB[tid] = bsc[tid];

  __syncthreads();                          // the ONE vmcnt join: emb + W landed

  f32x4 acc[2][8];
#pragma unroll
  for (int nt = 0; nt < 8; ++nt) {
    f32x4 bv = *(const f32x4*)(LB + nt * 16 + q * 4);
    acc[0][nt] = bv;
    acc[1][nt] = bv;
  }
#pragma unroll
  for (int ks = 0; ks < 4; ++ks) {
    s16x8 ef0 = cvt8(ea0[ks], eb0[ks]);
    s16x8 ef1 = cvt8(ea1[ks], eb1[ks]);
#pragma unroll
    for (int nt = 0; nt < 8; ++nt) {
      s16x8 wf = *(const s16x8*)((const char*)WL + (ks * 8 + nt) * 1024 + lane * 16);
      acc[0][nt] = __builtin_amdgcn_mfma_f32_16x16x32_bf16(wf, ef0, acc[0][nt], 0, 0, 0);
      acc[1][nt] = __builtin_amdgcn_mfma_f32_16x16x32_bf16(wf, ef1, acc[1][nt], 0, 0, 0);
    }
  }

  // stage fp8 (row rt*16+cl, u32 col nt*4+q), pitch 144B
  char* sw = &ST[wv][0];
#pragma unroll
  for (int rt = 0; rt < 2; ++rt)
#pragma unroll
    for (int nt = 0; nt < 8; ++nt) {
      unsigned pk = enc4(acc[rt][nt][0], acc[rt][nt][1], acc[rt][nt][2], acc[rt][nt][3]);
      *(unsigned*)(sw + (rt * 16 + cl) * 144 + (nt * 4 + q) * 4) = pk;
    }
  asm volatile("s_waitcnt lgkmcnt(0)" ::: "memory");
  __builtin_amdgcn_sched_barrier(0);

  // drain: 4 x (ds_read_b128 + 16B store), 4KB contiguous per wave; tail masked
#pragma unroll
  for (int j = 0; j < 4; ++j) {
    const int slot = j * 64 + lane;         // 0..255
    const int rr = slot >> 3, c16 = slot & 7;
    const long grow = rowbase + rr;
    if (grow < VOCAB) {
      u32x4 v = *(const u32x4*)(sw + rr * 144 + c16 * 16);
      *(u32x4*)&T8[grow * EDIM + c16 * 16] = v;
    }
  }
}

// ---------------- Probe: proj's exact memory skeleton (no MFMA/LDS/enc) ----------------
// Same grid (1563x256), same lane->address map, 16 f32x4 loads, XOR-fold, 1 u32 store.
// Runs LAST (emb is L3-warm from proj, matching probe R13's warm regime).
__global__ __launch_bounds__(256) void skel_kernel(
    const float* __restrict__ emb, unsigned* __restrict__ sink) {
  const int tid = threadIdx.x;
  const int wv = tid >> 6, lane = tid & 63;
  const int q = lane >> 4, cl = lane & 15;
  const long rowbase = (long)blockIdx.x * 128 + wv * 32;
  long r0 = rowbase + cl, r1 = rowbase + 16 + cl;
  if (r0 >= VOCAB) r0 = VOCAB - 1;
  if (r1 >= VOCAB) r1 = VOCAB - 1;
  const float* p0 = emb + r0 * EDIM + q * 8;
  const float* p1 = emb + r1 * EDIM + q * 8;
  f32x4 x = {0.f, 0.f, 0.f, 0.f};
#pragma unroll
  for (int ks = 0; ks < 4; ++ks) {
    f32x4 a0 = *(const f32x4*)(p0 + ks * 32);
    f32x4 b0 = *(const f32x4*)(p0 + ks * 32 + 4);
    f32x4 a1 = *(const f32x4*)(p1 + ks * 32);
    f32x4 b1 = *(const f32x4*)(p1 + ks * 32 + 4);
    u32x4 u = __builtin_bit_cast(u32x4, a0) ^ __builtin_bit_cast(u32x4, b0) ^
              __builtin_bit_cast(u32x4, a1) ^ __builtin_bit_cast(u32x4, b1);
    x = __builtin_bit_cast(f32x4, __builtin_bit_cast(u32x4, x) ^ u);
  }
  u32x4 u = __builtin_bit_cast(u32x4, x);
  sink[(long)blockIdx.x * 256 + tid] = u[0] ^ u[1] ^ u[2] ^ u[3];
}

// ---------------- Kernel 2: one block = one tree (unchanged — ~9 us) ----------------
__global__ __launch_bounds__(512, 4) void tree_kernel(
    const unsigned char* __restrict__ T8, const int* __restrict__ tokens,
    float* __restrict__ out) {
  __shared__ unsigned char P8[512][EDIM];          // 64 KiB
  unsigned char* lds = &P8[0][0];
  const int SOFF = 16384;
  const int MOFF = 53248;

  const int tid = threadIdx.x;
  const int tree = blockIdx.x;
  const int wv = tid >> 6, lane = tid & 63;

  const int* tk = tokens + (long)tree * KNODES;
  int toks[8];
#pragma unroll
  for (int i = 0; i < 8; ++i) {
    int node = wv * 64 + i * 8 + (lane >> 3);
    toks[i] = tk[node > 510 ? 510 : node];
  }
  const int chunk = (lane & 7) ^ ((lane >> 3) & 7);
#pragma unroll
  for (int i = 0; i < 8; ++i) {
    const unsigned char* src = T8 + (long)toks[i] * EDIM + chunk * 16;
    unsigned char* dst = &P8[wv * 64 + i * 8][0];
    __builtin_amdgcn_global_load_lds((const AS1 unsigned int*)src,
                                     (AS3 unsigned int*)dst, 16, 0, 0);
  }
  __syncthreads();

  auto ldP8 = [&](int row, int q8) -> uint2 {
    int g = q8 >> 1, h = q8 & 1;
    return *(const uint2*)(lds + row * 128 + (((g ^ (row & 7))) << 4) + h * 8);
  };
  auto saddr = [&](int slot, int q16) -> unsigned char* {
    return lds + SOFF + slot * 288 + ((q16 ^ (slot & 7)) << 4);
  };

  const int q = tid & 15;
  const int jg = tid >> 4;
  float rmax[8];
#pragma unroll
  for (int e = 0; e < 8; ++e) rmax[e] = 0.f;

  u16x8 sp7[4];
#pragma unroll
  for (int k = 0; k < 4; ++k) {
    const int p = jg + 32 * k, m = 127 + p;
    uint2 pr = ldP8(m, q);
    uint2 xr = ldP8(2 * m + 1, q);
    uint2 yr = ldP8(2 * m + 2, q);
    float pv[8], xv[8], yv[8];
    dec8(pr, pv); dec8(xr, xv); dec8(yr, yv);
#pragma unroll
    for (int e = 0; e < 8; ++e) {
      float sv = pv[e] + xv[e] + yv[e];
      rmax[e] = fmaxf(rmax[e], fmaxf(fmaxf(xv[e], yv[e]), sv));
      sp7[k][e] = f2bf(sv);
    }
  }
  __syncthreads();
#pragma unroll
  for (int k = 0; k < 4; ++k) *(u16x8*)saddr(jg + 32 * k, q) = sp7[k];
  __syncthreads();

  for (int l = 6; l >= 0; --l) {
    const int cnt = 1 << l;
    for (int p = jg; p < cnt; p += 32) {
      const int m = cnt - 1 + p;
      const int ps = p << (7 - l);
      const int c2s = ps + (1 << (6 - l));
      uint2 pr = ldP8(m, q);
      u16x8 c1 = *(const u16x8*)saddr(ps, q);
      u16x8 c2 = *(const u16x8*)saddr(c2s, q);
      float pv[8];
      dec8(pr, pv);
      u16x8 sp;
#pragma unroll
      for (int e = 0; e < 8; ++e) {
        float sv = pv[e] + bf2f(c1[e]) + bf2f(c2[e]);
        rmax[e] = fmaxf(rmax[e], sv);
        sp[e] = f2bf(sv);
      }
      *(u16x8*)saddr(ps, q) = sp;
    }
    __syncthreads();
  }

#pragma unroll
  for (int e = 0; e < 8; ++e) {
    rmax[e] = fmaxf(rmax[e], __shfl_xor(rmax[e], 16, 64));
    rmax[e] = fmaxf(rmax[e], __shfl_xor(rmax[e], 32, 64));
  }
  float* mb = (float*)(lds + MOFF);
  if (lane < 16) {
#pragma unroll
    for (int e = 0; e < 8; ++e) mb[wv * 128 + lane * 8 + e] = rmax[e];
  }
  __syncthreads();
  if (tid < 128) {
    float v = mb[tid];
#pragma unroll
    for (int w2 = 1; w2 < 8; ++w2) v = fmaxf(v, mb[w2 * 128 + tid]);
    out[(long)tree * 128 + tid] = v * 0.015625f;
  }
}

extern "C" void kernel_launch(void* const* d_in, const int* in_sizes, int n_in,
                              void* d_out, int out_size, void* d_ws, size_t ws_size,
                              hipStream_t stream) {
  const float* emb = (const float*)d_in[0];
  const float* W = (const float*)d_in[1];
  const float* b = (const float*)d_in[2];
  const int* tokens = (const int*)d_in[3];

  unsigned char* T8 = (unsigned char*)d_ws;                           // 25.6 MB @ 0
  unsigned short* WTb2 = (unsigned short*)((char*)d_ws + (32 << 20)); // 32 KB @ 32MB
  float* bsc = (float*)((char*)d_ws + (32 << 20) + 32768);            // 512 B
  unsigned* sink = (unsigned*)((char*)d_ws + (40 << 20));             // 1.6 MB @ 40MB
  float* out = (float*)d_out;

  wprep_kernel<<<8, 256, 0, stream>>>(W, b, WTb2, bsc);
  proj_kernel<<<1563, 256, 0, stream>>>(emb, WTb2, bsc, T8);
  tree_kernel<<<NTREES, 512, 0, stream>>>(T8, tokens, out);
  skel_kernel<<<1563, 256, 0, stream>>>(emb, sink);   // probe LAST (post-warm)
}

// Round 17
// 63.119 us; speedup vs baseline: 1.3073x; 1.3073x over previous
//
#include <hip/hip_runtime.h>
#include <hip/hip_bf16.h>
#include <stdint.h>

#define VOCAB 200000
#define EDIM 128
#define NTREES 2048
#define KNODES 511

typedef __attribute__((ext_vector_type(4))) float f32x4;
typedef __attribute__((ext_vector_type(2))) float f32x2;
typedef __attribute__((ext_vector_type(8))) short s16x8;
typedef __attribute__((ext_vector_type(8))) unsigned short u16x8;
typedef __attribute__((ext_vector_type(4))) unsigned int u32x4;

#define AS1 __attribute__((address_space(1)))
#define AS3 __attribute__((address_space(3)))

__device__ __forceinline__ unsigned short f2bf(float x) {
  unsigned u = __builtin_bit_cast(unsigned, x);
  return (unsigned short)((u + 0x7fffu + ((u >> 16) & 1u)) >> 16);  // RNE
}
__device__ __forceinline__ float bf2f(unsigned short h) {
  unsigned u = ((unsigned)h) << 16;
  return __builtin_bit_cast(float, u);
}

// ---- manual OCP e4m3fn codec (fallback paths only) ----
__device__ __forceinline__ unsigned fp8enc(float v) {
  unsigned u = __builtin_bit_cast(unsigned, v);
  unsigned s = (u >> 24) & 0x80u;
  unsigned au = u & 0x7fffffffu;
  au = au > 0x43E00000u ? 0x43E00000u : au;
  unsigned r = au + 0x0007ffffu + ((au >> 20) & 1u);
  unsigned code = (((r >> 23) - 120u) << 3) | ((r >> 20) & 7u);
  float a = __builtin_bit_cast(float, au);
  unsigned sub = (unsigned)(int)rintf(a * 512.0f);
  unsigned c = (au < 0x3C800000u) ? sub : code;
  return c | s;
}
__device__ __forceinline__ float fp8dec(unsigned b) {
  unsigned e = (b >> 3) & 15u, m = b & 7u;
  float n = __builtin_bit_cast(float, ((e + 120u) << 23) | (m << 20));
  float sv = (float)(int)m * 0.001953125f;
  float v = e ? n : sv;
  return (b & 0x80u) ? -v : v;
}

__device__ __forceinline__ unsigned enc4(float a, float b, float c, float d) {
#if __has_builtin(__builtin_amdgcn_cvt_pk_fp8_f32)
  int pk = 0;
  pk = __builtin_amdgcn_cvt_pk_fp8_f32(a, b, pk, false);
  pk = __builtin_amdgcn_cvt_pk_fp8_f32(c, d, pk, true);
  return (unsigned)pk;
#else
  return fp8enc(a) | (fp8enc(b) << 8) | (fp8enc(c) << 16) | (fp8enc(d) << 24);
#endif
}

__device__ __forceinline__ void dec8(uint2 v, float* o) {
#if __has_builtin(__builtin_amdgcn_cvt_pk_f32_fp8)
  f32x2 a = __builtin_amdgcn_cvt_pk_f32_fp8(v.x, false);
  f32x2 b = __builtin_amdgcn_cvt_pk_f32_fp8(v.x, true);
  f32x2 c = __builtin_amdgcn_cvt_pk_f32_fp8(v.y, false);
  f32x2 d = __builtin_amdgcn_cvt_pk_f32_fp8(v.y, true);
  o[0] = a[0]; o[1] = a[1]; o[2] = b[0]; o[3] = b[1];
  o[4] = c[0]; o[5] = c[1]; o[6] = d[0]; o[7] = d[1];
#else
#pragma unroll
  for (int i = 0; i < 4; ++i) o[i] = fp8dec((v.x >> (8 * i)) & 0xFFu);
#pragma unroll
  for (int i = 0; i < 4; ++i) o[4 + i] = fp8dec((v.y >> (8 * i)) & 0xFFu);
#endif
}

__device__ __forceinline__ s16x8 cvt8(f32x4 a, f32x4 b) {
  u16x8 t;
#pragma unroll
  for (int i = 0; i < 4; ++i)
    t[i] = __builtin_bit_cast(unsigned short, __float2bfloat16(a[i]));
#pragma unroll
  for (int i = 0; i < 4; ++i)
    t[4 + i] = __builtin_bit_cast(unsigned short, __float2bfloat16(b[i]));
  return __builtin_bit_cast(s16x8, t);
}

// ---------------- Kernel 0: one-shot W/bias prep, fragment-major ----------------
__global__ __launch_bounds__(256) void wprep_kernel(
    const float* __restrict__ W, const float* __restrict__ b,
    unsigned short* __restrict__ WTb2, float* __restrict__ bsc) {
  int c = blockIdx.x * 256 + threadIdx.x;   // 0..2047
  if (c < 2048) {
    int lane = c & 63, fr = c >> 6;
    int ks = fr >> 3, nt = fr & 7, q = lane >> 4, cl = lane & 15;
    u16x8 t;
#pragma unroll
    for (int j = 0; j < 8; ++j)
      t[j] = f2bf(W[(ks * 32 + q * 8 + j) * EDIM + nt * 16 + cl] * 64.0f);
    *(u16x8*)(WTb2 + c * 8) = t;
  }
  if (c < EDIM) bsc[c] = b[c] * 64.0f;
}

// ---------------- Kernel 1: T8 = fp8( emb @ W*64 + b*64 ) — max-residency one-shot ----------------
// v13: 64-row blocks (3125, 12.2/CU), LDS cut to 32.5 KiB (WL reused as store-stage
// after a barrier) -> 4 blocks/CU resident; ~128 KiB of emb loads in flight per CU
// continuously (skel-like). 8 batched+pinned loads/thread, ONE vmcnt join, 32 MFMAs,
// coalesced 2KB/wave stores. No tail (200000 = 3125*64).
__global__ __launch_bounds__(256, 4) void proj_kernel(
    const float* __restrict__ emb, const unsigned short* __restrict__ WTb2,
    const float* __restrict__ bsc, unsigned char* __restrict__ T8) {
  __shared__ unsigned short WL[2048 * 8];   // 32 KiB fragment-major; reused as store stage
  __shared__ float LB[EDIM];                // 512 B

  const int tid = threadIdx.x;
  const int wv = tid >> 6, lane = tid & 63;
  const int q = lane >> 4, cl = lane & 15;

  // batched emb working set: 8 independent f32x4 loads (rows rowbase..+15 per wave)
  const long rowbase = (long)blockIdx.x * 64 + wv * 16;
  const float* p0 = emb + (rowbase + cl) * EDIM + q * 8;
  f32x4 ea[4], eb[4];
#pragma unroll
  for (int ks = 0; ks < 4; ++ks) {
    ea[ks] = *(const f32x4*)(p0 + ks * 32);
    eb[ks] = *(const f32x4*)(p0 + ks * 32 + 4);
  }

  // stage W into LDS (8 x 1KB DMA per wave, linear dest) + bias
#pragma unroll
  for (int i = 0; i < 8; ++i) {
    const char* src = (const char*)WTb2 + wv * 8192 + i * 1024 + lane * 16;
    char* dstp = (char*)WL + wv * 8192 + i * 1024;
    __builtin_amdgcn_global_load_lds((const AS1 unsigned int*)src,
                                     (AS3 unsigned int*)dstp, 16, 0, 0);
  }
  if (tid < EDIM) LB[tid] = bsc[tid];

  // pin loads (no sinking into the MFMA loop), then the ONE join
#pragma unroll
  for (int ks = 0; ks < 4; ++ks) {
    asm volatile("" : "+v"(ea[ks]));
    asm volatile("" : "+v"(eb[ks]));
  }
  __syncthreads();                          // emb + W landed

  f32x4 acc[8];
#pragma unroll
  for (int nt = 0; nt < 8; ++nt) acc[nt] = *(const f32x4*)(LB + nt * 16 + q * 4);
#pragma unroll
  for (int ks = 0; ks < 4; ++ks) {
    s16x8 ef = cvt8(ea[ks], eb[ks]);
#pragma unroll
    for (int nt = 0; nt < 8; ++nt) {
      s16x8 wf = *(const s16x8*)((const char*)WL + (ks * 8 + nt) * 1024 + lane * 16);
      acc[nt] = __builtin_amdgcn_mfma_f32_16x16x32_bf16(wf, ef, acc[nt], 0, 0, 0);
    }
  }

  __syncthreads();                          // all wf reads done -> WL reusable

  // stage fp8 into this wave's dead WL region (16 rows x 144B pitch)
  char* sw = (char*)WL + wv * 8192 + cl * 144;
#pragma unroll
  for (int nt = 0; nt < 8; ++nt) {
    unsigned pk = enc4(acc[nt][0], acc[nt][1], acc[nt][2], acc[nt][3]);
    *(unsigned*)(sw + (nt * 4 + q) * 4) = pk;
  }
  asm volatile("s_waitcnt lgkmcnt(0)" ::: "memory");
  __builtin_amdgcn_sched_barrier(0);

  // drain: 2 x (ds_read_b128 + 16B store), 2KB contiguous per wave
  const long tb8 = rowbase * EDIM;          // byte base (T8 row = 128 B)
#pragma unroll
  for (int j = 0; j < 2; ++j) {
    const int slot = j * 64 + lane;         // 16B chunk 0..127
    const int rr = slot >> 3, c16 = slot & 7;
    u32x4 v = *(const u32x4*)((char*)WL + wv * 8192 + rr * 144 + c16 * 16);
    *(u32x4*)&T8[tb8 + slot * 16] = v;
  }
}

// ---------------- Kernel 2: one block = one tree (unchanged — ~9 us) ----------------
__global__ __launch_bounds__(512, 4) void tree_kernel(
    const unsigned char* __restrict__ T8, const int* __restrict__ tokens,
    float* __restrict__ out) {
  __shared__ unsigned char P8[512][EDIM];          // 64 KiB
  unsigned char* lds = &P8[0][0];
  const int SOFF = 16384;
  const int MOFF = 53248;

  const int tid = threadIdx.x;
  const int tree = blockIdx.x;
  const int wv = tid >> 6, lane = tid & 63;

  const int* tk = tokens + (long)tree * KNODES;
  int toks[8];
#pragma unroll
  for (int i = 0; i < 8; ++i) {
    int node = wv * 64 + i * 8 + (lane >> 3);
    toks[i] = tk[node > 510 ? 510 : node];
  }
  const int chunk = (lane & 7) ^ ((lane >> 3) & 7);
#pragma unroll
  for (int i = 0; i < 8; ++i) {
    const unsigned char* src = T8 + (long)toks[i] * EDIM + chunk * 16;
    unsigned char* dst = &P8[wv * 64 + i * 8][0];
    __builtin_amdgcn_global_load_lds((const AS1 unsigned int*)src,
                                     (AS3 unsigned int*)dst, 16, 0, 0);
  }
  __syncthreads();

  auto ldP8 = [&](int row, int q8) -> uint2 {
    int g = q8 >> 1, h = q8 & 1;
    return *(const uint2*)(lds + row * 128 + (((g ^ (row & 7))) << 4) + h * 8);
  };
  auto saddr = [&](int slot, int q16) -> unsigned char* {
    return lds + SOFF + slot * 288 + ((q16 ^ (slot & 7)) << 4);
  };

  const int q = tid & 15;
  const int jg = tid >> 4;
  float rmax[8];
#pragma unroll
  for (int e = 0; e < 8; ++e) rmax[e] = 0.f;

  u16x8 sp7[4];
#pragma unroll
  for (int k = 0; k < 4; ++k) {
    const int p = jg + 32 * k, m = 127 + p;
    uint2 pr = ldP8(m, q);
    uint2 xr = ldP8(2 * m + 1, q);
    uint2 yr = ldP8(2 * m + 2, q);
    float pv[8], xv[8], yv[8];
    dec8(pr, pv); dec8(xr, xv); dec8(yr, yv);
#pragma unroll
    for (int e = 0; e < 8; ++e) {
      float sv = pv[e] + xv[e] + yv[e];
      rmax[e] = fmaxf(rmax[e], fmaxf(fmaxf(xv[e], yv[e]), sv));
      sp7[k][e] = f2bf(sv);
    }
  }
  __syncthreads();
#pragma unroll
  for (int k = 0; k < 4; ++k) *(u16x8*)saddr(jg + 32 * k, q) = sp7[k];
  __syncthreads();

  for (int l = 6; l >= 0; --l) {
    const int cnt = 1 << l;
    for (int p = jg; p < cnt; p += 32) {
      const int m = cnt - 1 + p;
      const int ps = p << (7 - l);
      const int c2s = ps + (1 << (6 - l));
      uint2 pr = ldP8(m, q);
      u16x8 c1 = *(const u16x8*)saddr(ps, q);
      u16x8 c2 = *(const u16x8*)saddr(c2s, q);
      float pv[8];
      dec8(pr, pv);
      u16x8 sp;
#pragma unroll
      for (int e = 0; e < 8; ++e) {
        float sv = pv[e] + bf2f(c1[e]) + bf2f(c2[e]);
        rmax[e] = fmaxf(rmax[e], sv);
        sp[e] = f2bf(sv);
      }
      *(u16x8*)saddr(ps, q) = sp;
    }
    __syncthreads();
  }

#pragma unroll
  for (int e = 0; e < 8; ++e) {
    rmax[e] = fmaxf(rmax[e], __shfl_xor(rmax[e], 16, 64));
    rmax[e] = fmaxf(rmax[e], __shfl_xor(rmax[e], 32, 64));
  }
  float* mb = (float*)(lds + MOFF);
  if (lane < 16) {
#pragma unroll
    for (int e = 0; e < 8; ++e) mb[wv * 128 + lane * 8 + e] = rmax[e];
  }
  __syncthreads();
  if (tid < 128) {
    float v = mb[tid];
#pragma unroll
    for (int w2 = 1; w2 < 8; ++w2) v = fmaxf(v, mb[w2 * 128 + tid]);
    out[(long)tree * 128 + tid] = v * 0.015625f;
  }
}

extern "C" void kernel_launch(void* const* d_in, const int* in_sizes, int n_in,
                              void* d_out, int out_size, void* d_ws, size_t ws_size,
                              hipStream_t stream) {
  const float* emb = (const float*)d_in[0];
  const float* W = (const float*)d_in[1];
  const float* b = (const float*)d_in[2];
  const int* tokens = (const int*)d_in[3];

  unsigned char* T8 = (unsigned char*)d_ws;                           // 25.6 MB @ 0
  unsigned short* WTb2 = (unsigned short*)((char*)d_ws + (32 << 20)); // 32 KB @ 32MB
  float* bsc = (float*)((char*)d_ws + (32 << 20) + 32768);            // 512 B
  float* out = (float*)d_out;

  wprep_kernel<<<8, 256, 0, stream>>>(W, b, WTb2, bsc);
  proj_kernel<<<VOCAB / 64, 256, 0, stream>>>(emb, WTb2, bsc, T8);    // 3125 blocks
  tree_kernel<<<NTREES, 512, 0, stream>>>(T8, tokens, out);
}